// Round 5
// baseline (893.207 us; speedup 1.0000x reference)
//
#include <hip/hip_runtime.h>
#include <hip/hip_bf16.h>
#include <cstdint>

#define NN 50000
#define NE 1600000
#define DV 256
#define DA 128

using floatx4 = __attribute__((ext_vector_type(4))) float;
using shortx8 = __attribute__((ext_vector_type(8))) short;

__device__ __forceinline__ unsigned short f2bf(float f) {
    union { float f; uint32_t u; } v; v.f = f;
    uint32_t u = v.u;
    uint32_t r = (u + 0x7FFFu + ((u >> 16) & 1u)) >> 16;   // RNE
    return (unsigned short)r;
}
__device__ __forceinline__ float bflo(uint32_t u) {
    union { uint32_t u; float f; } v; v.u = u << 16; return v.f;
}
__device__ __forceinline__ float bfhi(uint32_t u) {
    union { uint32_t u; float f; } v; v.u = u & 0xFFFF0000u; return v.f;
}
__device__ __forceinline__ shortx8 pack8(float4 a, float4 b) {
    shortx8 u;
    u[0] = (short)f2bf(a.x); u[1] = (short)f2bf(a.y);
    u[2] = (short)f2bf(a.z); u[3] = (short)f2bf(a.w);
    u[4] = (short)f2bf(b.x); u[5] = (short)f2bf(b.y);
    u[6] = (short)f2bf(b.z); u[7] = (short)f2bf(b.w);
    return u;
}

// ---------------- zero out + denom + cnt ----------------------------------
__global__ void init_zero(float4* __restrict__ out, float4* __restrict__ denom,
                          float4* __restrict__ cnt) {
    const float4 z = make_float4(0.f, 0.f, 0.f, 0.f);
    int i = blockIdx.x * blockDim.x + threadIdx.x;
    const int stride = gridDim.x * blockDim.x;
    for (int j = i; j < NN * 128 / 4; j += stride) out[j] = z;
    if (i < NN / 4) { denom[i] = z; cnt[i] = z; }
}

// ---------------- cast weights fp32 -> bf16 -------------------------------
__global__ void cast_w_kernel(const float* __restrict__ wq, const float* __restrict__ wk,
                              const float* __restrict__ wv, unsigned short* __restrict__ out) {
    int i = blockIdx.x * blockDim.x + threadIdx.x;
    if (i < 32768)       out[i] = f2bf(wq[i]);
    else if (i < 65536)  out[i] = f2bf(wk[i - 32768]);
    else if (i < 81920)  out[i] = f2bf(wv[i - 65536]);
}

// ---------------- sort-by-receiver infrastructure -------------------------
__global__ void hist_kernel(const int* __restrict__ ridx, int* __restrict__ cnt) {
    int e = blockIdx.x * blockDim.x + threadIdx.x;
    if (e < NE) atomicAdd(&cnt[ridx[e]], 1);
}

__global__ __launch_bounds__(1024)
void scan_kernel(const int* __restrict__ cnt, int* __restrict__ offs) {
    __shared__ int part[1024];
    const int tid = threadIdx.x;
    const int PER = (NN + 1023) / 1024;   // 49
    int base = tid * PER;
    int s = 0;
    for (int i = 0; i < PER; ++i) { int idx = base + i; if (idx < NN) s += cnt[idx]; }
    part[tid] = s;
    __syncthreads();
    for (int off = 1; off < 1024; off <<= 1) {
        int v = (tid >= off) ? part[tid - off] : 0;
        __syncthreads();
        part[tid] += v;
        __syncthreads();
    }
    int excl = (tid == 0) ? 0 : part[tid - 1];
    for (int i = 0; i < PER; ++i) {
        int idx = base + i;
        if (idx < NN) { offs[idx] = excl; excl += cnt[idx]; }
    }
}

__global__ void scatter_kernel(const int* __restrict__ ridx, int* __restrict__ offs,
                               int* __restrict__ perm) {
    int e = blockIdx.x * blockDim.x + threadIdx.x;
    if (e >= NE) return;
    int r = ridx[e];
    int pos = atomicAdd(&offs[r], 1);
    perm[pos] = e;
}

// ---------------- fused Q,K projection: [NN,256] x [256,256]^T ------------
__global__ __launch_bounds__(256)
void proj_qk(const float* __restrict__ A, const unsigned short* __restrict__ Wst,
             const float* __restrict__ bq, const float* __restrict__ bk,
             unsigned short* __restrict__ qbf, unsigned short* __restrict__ kbf, int M) {
    __shared__ unsigned short Al[64 * 32];
    __shared__ unsigned short Bl[256 * 32];
    const int tid = threadIdx.x;
    const int lane = tid & 63, w = tid >> 6;
    const int m0 = blockIdx.x * 64;
    constexpr int K = 256;

    floatx4 acc[16];
#pragma unroll
    for (int i = 0; i < 16; ++i) acc[i] = (floatx4)0.0f;

    for (int kk = 0; kk < K; kk += 32) {
#pragma unroll
        for (int it = 0; it < 2; ++it) {
            int j = tid + it * 256;
            int row = j >> 3;
            int c4 = (j & 7) * 4;
            float4 f = make_float4(0.f, 0.f, 0.f, 0.f);
            int gm = m0 + row;
            if (gm < M) f = *reinterpret_cast<const float4*>(A + (size_t)gm * K + kk + c4);
            ushort4 u; u.x = f2bf(f.x); u.y = f2bf(f.y); u.z = f2bf(f.z); u.w = f2bf(f.w);
            *reinterpret_cast<ushort4*>(&Al[row * 32 + c4]) = u;
        }
#pragma unroll
        for (int it = 0; it < 4; ++it) {
            int j = tid + it * 256;
            int row = j >> 2;
            int c8 = (j & 3) * 8;
            uint4 v = *reinterpret_cast<const uint4*>(Wst + (size_t)row * K + kk + c8);
            *reinterpret_cast<uint4*>(&Bl[row * 32 + c8]) = v;
        }
        __syncthreads();
        shortx8 af = *reinterpret_cast<const shortx8*>(&Al[(w * 16 + (lane & 15)) * 32 + 8 * (lane >> 4)]);
#pragma unroll
        for (int nt = 0; nt < 16; ++nt) {
            shortx8 bf = *reinterpret_cast<const shortx8*>(&Bl[(nt * 16 + (lane & 15)) * 32 + 8 * (lane >> 4)]);
            acc[nt] = __builtin_amdgcn_mfma_f32_16x16x32_bf16(af, bf, acc[nt], 0, 0, 0);
        }
        __syncthreads();
    }
    const int col = lane & 15;
    const int rbase = m0 + w * 16 + 4 * (lane >> 4);
#pragma unroll
    for (int nt = 0; nt < 16; ++nt) {
        int gn = nt * 16 + col;
        bool isq = gn < 128;
        int oc = isq ? gn : gn - 128;
        float b = isq ? bq[oc] : bk[oc];
        unsigned short* O = isq ? qbf : kbf;
#pragma unroll
        for (int reg = 0; reg < 4; ++reg) {
            int gm = rbase + reg;
            if (gm < M) {
                float v = acc[nt][reg] + b;
                v = v > 0.f ? v : 0.01f * v;
                O[(size_t)gm * 128 + oc] = f2bf(v);
            }
        }
    }
}

// ---- fused: logits+exp, V projection, segment reduce ----------------------
// BM=128 edges/block, 512 threads (8 waves).
// KEY CHANGE vs r4: each gathered edge row's full 512B is read in ONE burst
// (DRAM page efficiency), whole A tile staged to LDS fragment-linear in the
// prologue; K-loop is barrier-free (4 kt x 8 nt MFMAs straight from LDS).
// LDS map (bytes), total 67616:
//   [0,32768)       Bf: Wv fragments (kt,nt) | aliased post-loop: Vl bf16 [128][128]
//   [32768,65536)   A fragments: frag_id = w*4+kt, 1KB each (lane*16B)
//   [65536,66048)   rs_local[128] int
//   [66048,66560)   pl[128] float
//   [66560,67072)   segstart[128] int
//   [67072,67584)   segnode[128] int
//   [67584,67600)   masks[2] u64
//   [67600,67604)   nseg int
__global__ __launch_bounds__(512)
void v_gemm_fused(const float* __restrict__ Ed, const unsigned short* __restrict__ wv_bf,
                  const float* __restrict__ bv,
                  const unsigned short* __restrict__ qbf, const unsigned short* __restrict__ kbf,
                  const int* __restrict__ sidx, const int* __restrict__ ridx,
                  const int* __restrict__ perm,
                  float* __restrict__ out, float* __restrict__ denom) {
    __shared__ __align__(16) char smem[67616];
    unsigned short* Vl = reinterpret_cast<unsigned short*>(smem);        // alias of Bf, post-loop
    int*   rs_local = reinterpret_cast<int*>(smem + 65536);
    float* pl       = reinterpret_cast<float*>(smem + 66048);
    int*   segstart = reinterpret_cast<int*>(smem + 66560);
    int*   segnode  = reinterpret_cast<int*>(smem + 67072);
    unsigned long long* masks = reinterpret_cast<unsigned long long*>(smem + 67584);
    int* nseg_s = reinterpret_cast<int*>(smem + 67600);

    const int tid = threadIdx.x;
    const int lane = tid & 63, w = tid >> 6;

    // bijective XCD swizzle (m204): nwg=12500, q=1562, r=4 -> XCD gets contiguous range
    const int bid = blockIdx.x;
    const int xcd = bid & 7;
    const int nbid = ((xcd < 4) ? xcd * 1563 : 4 * 1563 + (xcd - 4) * 1562) + (bid >> 3);
    const size_t m0 = (size_t)nbid * 128;          // NE % 128 == 0

    // ---- prologue ----
    const int erow = tid >> 2;                     // 0..127 edge slot
    const int qt = tid & 3;                        // k-chunk / logit quarter
    const int e_id = perm[m0 + erow];
    const int sN = sidx[e_id];
    const int rN = ridx[e_id];
    if (qt == 0) rs_local[erow] = rN;

    // edge row: this thread owns 128B = floats qt*32..+31, read as one burst
    const float* arow = Ed + (size_t)e_id * 128;
    float4 fa[4], fb[4];
#pragma unroll
    for (int ks = 0; ks < 4; ++ks) {
        fa[ks] = *reinterpret_cast<const float4*>(arow + qt * 32 + ks * 8);
        fb[ks] = *reinterpret_cast<const float4*>(arow + qt * 32 + ks * 8 + 4);
    }

    // logits: 4 lanes per edge, 32 dims each (q/k are L2/L3-resident)
    {
        const uint4* kp = reinterpret_cast<const uint4*>(kbf + (size_t)sN * 128 + qt * 32);
        const uint4* qp = reinterpret_cast<const uint4*>(qbf + (size_t)rN * 128 + qt * 32);
        float acq = 0.f;
#pragma unroll
        for (int i = 0; i < 4; ++i) {
            uint4 qa = qp[i], ka = kp[i];
            acq += bflo(qa.x) * bflo(ka.x) + bfhi(qa.x) * bfhi(ka.x);
            acq += bflo(qa.y) * bflo(ka.y) + bfhi(qa.y) * bfhi(ka.y);
            acq += bflo(qa.z) * bflo(ka.z) + bfhi(qa.z) * bfhi(ka.z);
            acq += bflo(qa.w) * bflo(ka.w) + bfhi(qa.w) * bfhi(ka.w);
        }
        acq += __shfl_xor(acq, 1);
        acq += __shfl_xor(acq, 2);
        if (qt == 0) pl[erow] = __expf(acq * 0.08838834764831845f);
    }

    // Wv -> Bf fragment-linear (frag (kt,nt): lane l = B[k=kt*32+8*(l>>4)][n=nt*16+(l&15)])
#pragma unroll
    for (int it = 0; it < 4; ++it) {
        int s = tid + it * 512;
        int g = s >> 6, l = s & 63;
        int kt4 = g >> 3, nt = g & 7;
        uint4 v = *reinterpret_cast<const uint4*>(
            wv_bf + (size_t)(nt * 16 + (l & 15)) * 128 + kt4 * 32 + 8 * (l >> 4));
        *reinterpret_cast<uint4*>(smem + s * 16) = v;
    }

    // A -> fragment-linear: frag_id = (erow>>4)*4 + qt; lane = (erow&15) + 16*ks
    {
        const int fragbase = 32768 + (((erow >> 4) * 4 + qt) << 10) + ((erow & 15) << 4);
#pragma unroll
        for (int ks = 0; ks < 4; ++ks)
            *reinterpret_cast<shortx8*>(smem + fragbase + ks * 256) = pack8(fa[ks], fb[ks]);
    }
    __syncthreads();

    // segment masks over the 128 sorted receivers
    if (tid < 128) {
        bool flag = (tid == 0) || (rs_local[tid] != rs_local[tid - 1]);
        unsigned long long mk = __ballot(flag);
        if (lane == 0) masks[w] = mk;
    }
    __syncthreads();
    if (tid < 128) {
        bool flag = (tid == 0) || (rs_local[tid] != rs_local[tid - 1]);
        unsigned long long mk0 = masks[0], mk1 = masks[1];
        if (tid == 0) *nseg_s = __popcll(mk0) + __popcll(mk1);
        if (flag) {
            int rank = (tid < 64)
                ? __popcll(mk0 & ((1ull << tid) - 1ull))
                : __popcll(mk0) + ((tid == 64) ? 0 : __popcll(mk1 & ((1ull << (tid - 64)) - 1ull)));
            segstart[rank] = tid;
            segnode[rank] = rs_local[tid];
        }
    }
    // (segstart/segnode visibility to reduce phase covered by the barriers below)

    // ---- K loop: barrier-free, all operands in LDS ----
    floatx4 acc[8];
#pragma unroll
    for (int i = 0; i < 8; ++i) acc[i] = (floatx4)0.0f;
#pragma unroll
    for (int kt = 0; kt < 4; ++kt) {
        shortx8 af = *reinterpret_cast<const shortx8*>(
            smem + 32768 + ((w * 4 + kt) << 10) + (lane << 4));
#pragma unroll
        for (int nt = 0; nt < 8; ++nt) {
            shortx8 bfr = *reinterpret_cast<const shortx8*>(smem + (((kt * 8 + nt) * 64 + lane) << 4));
            acc[nt] = __builtin_amdgcn_mfma_f32_16x16x32_bf16(af, bfr, acc[nt], 0, 0, 0);
        }
    }
    __syncthreads();     // all Bf reads complete before aliasing as Vl

    // ---- epilogue: bias+lrelu, scale by p, stash bf16 rows (alias Bf) ----
    const int colb = lane & 15;
    const int rquad = w * 16 + 4 * (lane >> 4);
    float pe[4];
#pragma unroll
    for (int reg = 0; reg < 4; ++reg) pe[reg] = pl[rquad + reg];
#pragma unroll
    for (int nt = 0; nt < 8; ++nt) {
        float b = bv[nt * 16 + colb];
#pragma unroll
        for (int reg = 0; reg < 4; ++reg) {
            float v = acc[nt][reg] + b;
            v = v > 0.f ? v : 0.01f * v;
            Vl[(rquad + reg) * 128 + nt * 16 + colb] = f2bf(v * pe[reg]);
        }
    }
    __syncthreads();

    // ---- segment reduce: interior segments plain store, boundary atomic ----
    const int colc = tid & 127;
    const int sg = tid >> 7;                 // 4 segment streams
    const int ns = *nseg_s;
    for (int s2 = sg; s2 < ns; s2 += 4) {
        int a = segstart[s2];
        int bnd = (s2 + 1 < ns) ? segstart[s2 + 1] : 128;
        float sum = 0.f;
        for (int rr = a; rr < bnd; ++rr) sum += bflo((uint32_t)Vl[rr * 128 + colc]);
        int node = segnode[s2];
        bool interior = (s2 > 0) && (s2 + 1 < ns);
        if (interior) out[(size_t)node * 128 + colc] = sum;
        else          atomicAdd(&out[(size_t)node * 128 + colc], sum);
        if (colc == 0) {
            float ds = 0.f;
            for (int rr = a; rr < bnd; ++rr) ds += pl[rr];
            if (interior) denom[node] = ds;
            else          atomicAdd(&denom[node], ds);
        }
    }
}

// ---------------- normalize: out /= denom[node] ---------------------------
__global__ void normalize_kernel(float* __restrict__ out, const float* __restrict__ denom) {
    int i = blockIdx.x * blockDim.x + threadIdx.x;   // one float4 each
    if (i >= NN * 128 / 4) return;
    int node = (i * 4) >> 7;
    float d = denom[node];
    float inv = d > 0.f ? 1.0f / d : 0.f;
    float4* o = reinterpret_cast<float4*>(out) + i;
    float4 v = *o;
    v.x *= inv; v.y *= inv; v.z *= inv; v.w *= inv;
    *o = v;
}

extern "C" void kernel_launch(void* const* d_in, const int* in_sizes, int n_in,
                              void* d_out, int out_size, void* d_ws, size_t ws_size,
                              hipStream_t stream) {
    const float* nodes = (const float*)d_in[0];
    const float* edges = (const float*)d_in[1];
    const int*   eidx  = (const int*)d_in[2];     // row0 = sender, row1 = receiver
    const float* Wq = (const float*)d_in[3];
    const float* bq = (const float*)d_in[4];
    const float* Wk = (const float*)d_in[5];
    const float* bk = (const float*)d_in[6];
    const float* Wv = (const float*)d_in[7];
    const float* bv = (const float*)d_in[8];
    const int* sidx = eidx;
    const int* ridx = eidx + NE;

    // workspace layout (16B aligned):
    char* ws = (char*)d_ws;
    unsigned short* wq_bf = (unsigned short*)ws;          // Wq||Wk stacked, then Wv
    unsigned short* wv_bf = wq_bf + 65536;
    unsigned short* q_bf  = (unsigned short*)(ws + 163840);
    unsigned short* k_bf  = q_bf + (size_t)NN * 128;
    char* ws2 = ws + 163840 + 2 * (size_t)NN * 128 * 2;   // after q,k (25.6 MB)
    float* denom = (float*)ws2;                           // NN
    int*   cnt   = (int*)(denom + NN);                    // NN
    int*   offs  = cnt + NN;                              // NN
    int*   perm  = offs + NN;                             // NE
    float* out = (float*)d_out;

    init_zero<<<2048, 256, 0, stream>>>((float4*)out, (float4*)denom, (float4*)cnt);
    cast_w_kernel<<<320, 256, 0, stream>>>(Wq, Wk, Wv, wq_bf);
    hist_kernel<<<(NE + 255) / 256, 256, 0, stream>>>(ridx, cnt);
    scan_kernel<<<1, 1024, 0, stream>>>(cnt, offs);
    scatter_kernel<<<(NE + 255) / 256, 256, 0, stream>>>(ridx, offs, perm);
    proj_qk<<<(NN + 63) / 64, 256, 0, stream>>>(nodes, wq_bf, bq, bk, q_bf, k_bf, NN);
    v_gemm_fused<<<NE / 128, 512, 0, stream>>>(edges, wv_bf, bv, q_bf, k_bf, sidx, ridx,
                                               perm, out, denom);
    normalize_kernel<<<(NN * 128 / 4 + 255) / 256, 256, 0, stream>>>(out, denom);
}

// Round 6
// 879.039 us; speedup vs baseline: 1.0161x; 1.0161x over previous
//
#include <hip/hip_runtime.h>
#include <hip/hip_bf16.h>
#include <cstdint>

#define NN 50000
#define NE 1600000
#define DV 256
#define DA 128

using floatx4 = __attribute__((ext_vector_type(4))) float;
using shortx8 = __attribute__((ext_vector_type(8))) short;

__device__ __forceinline__ unsigned short f2bf(float f) {
    union { float f; uint32_t u; } v; v.f = f;
    uint32_t u = v.u;
    uint32_t r = (u + 0x7FFFu + ((u >> 16) & 1u)) >> 16;   // RNE
    return (unsigned short)r;
}
__device__ __forceinline__ float bflo(uint32_t u) {
    union { uint32_t u; float f; } v; v.u = u << 16; return v.f;
}
__device__ __forceinline__ float bfhi(uint32_t u) {
    union { uint32_t u; float f; } v; v.u = u & 0xFFFF0000u; return v.f;
}
__device__ __forceinline__ shortx8 pack8(float4 a, float4 b) {
    shortx8 u;
    u[0] = (short)f2bf(a.x); u[1] = (short)f2bf(a.y);
    u[2] = (short)f2bf(a.z); u[3] = (short)f2bf(a.w);
    u[4] = (short)f2bf(b.x); u[5] = (short)f2bf(b.y);
    u[6] = (short)f2bf(b.z); u[7] = (short)f2bf(b.w);
    return u;
}

// ---------------- zero cnt ------------------------------------------------
__global__ void init_cnt(int* __restrict__ cnt) {
    int i = blockIdx.x * blockDim.x + threadIdx.x;
    if (i < NN) cnt[i] = 0;
}

// ---------------- cast weights fp32 -> bf16 -------------------------------
__global__ void cast_w_kernel(const float* __restrict__ wq, const float* __restrict__ wk,
                              const float* __restrict__ wv, unsigned short* __restrict__ out) {
    int i = blockIdx.x * blockDim.x + threadIdx.x;
    if (i < 32768)       out[i] = f2bf(wq[i]);
    else if (i < 65536)  out[i] = f2bf(wk[i - 32768]);
    else if (i < 81920)  out[i] = f2bf(wv[i - 65536]);
}

// ---------------- sort-by-receiver infrastructure -------------------------
__global__ void hist_kernel(const int* __restrict__ ridx, int* __restrict__ cnt) {
    int e = blockIdx.x * blockDim.x + threadIdx.x;
    if (e < NE) atomicAdd(&cnt[ridx[e]], 1);
}

// single-block exclusive scan; writes cursor copy (offs) + pristine CSR (offs2)
__global__ __launch_bounds__(1024)
void scan_kernel(const int* __restrict__ cnt, int* __restrict__ offs, int* __restrict__ offs2) {
    __shared__ int part[1024];
    const int tid = threadIdx.x;
    const int PER = (NN + 1023) / 1024;   // 49
    int base = tid * PER;
    int s = 0;
    for (int i = 0; i < PER; ++i) { int idx = base + i; if (idx < NN) s += cnt[idx]; }
    part[tid] = s;
    __syncthreads();
    for (int off = 1; off < 1024; off <<= 1) {
        int v = (tid >= off) ? part[tid - off] : 0;
        __syncthreads();
        part[tid] += v;
        __syncthreads();
    }
    int excl = (tid == 0) ? 0 : part[tid - 1];
    for (int i = 0; i < PER; ++i) {
        int idx = base + i;
        if (idx < NN) { offs[idx] = excl; offs2[idx] = excl; excl += cnt[idx]; }
    }
    if (tid == 0) offs2[NN] = NE;
}

__global__ void scatter_kernel(const int* __restrict__ ridx, int* __restrict__ offs,
                               int* __restrict__ perm) {
    int e = blockIdx.x * blockDim.x + threadIdx.x;
    if (e >= NE) return;
    int r = ridx[e];
    int pos = atomicAdd(&offs[r], 1);
    perm[pos] = e;
}

// ---------------- fused Q,K projection: [NN,256] x [256,256]^T ------------
__global__ __launch_bounds__(256)
void proj_qk(const float* __restrict__ A, const unsigned short* __restrict__ Wst,
             const float* __restrict__ bq, const float* __restrict__ bk,
             unsigned short* __restrict__ qbf, unsigned short* __restrict__ kbf, int M) {
    __shared__ unsigned short Al[64 * 32];
    __shared__ unsigned short Bl[256 * 32];
    const int tid = threadIdx.x;
    const int lane = tid & 63, w = tid >> 6;
    const int m0 = blockIdx.x * 64;
    constexpr int K = 256;

    floatx4 acc[16];
#pragma unroll
    for (int i = 0; i < 16; ++i) acc[i] = (floatx4)0.0f;

    for (int kk = 0; kk < K; kk += 32) {
#pragma unroll
        for (int it = 0; it < 2; ++it) {
            int j = tid + it * 256;
            int row = j >> 3;
            int c4 = (j & 7) * 4;
            float4 f = make_float4(0.f, 0.f, 0.f, 0.f);
            int gm = m0 + row;
            if (gm < M) f = *reinterpret_cast<const float4*>(A + (size_t)gm * K + kk + c4);
            ushort4 u; u.x = f2bf(f.x); u.y = f2bf(f.y); u.z = f2bf(f.z); u.w = f2bf(f.w);
            *reinterpret_cast<ushort4*>(&Al[row * 32 + c4]) = u;
        }
#pragma unroll
        for (int it = 0; it < 4; ++it) {
            int j = tid + it * 256;
            int row = j >> 2;
            int c8 = (j & 3) * 8;
            uint4 v = *reinterpret_cast<const uint4*>(Wst + (size_t)row * K + kk + c8);
            *reinterpret_cast<uint4*>(&Bl[row * 32 + c8]) = v;
        }
        __syncthreads();
        shortx8 af = *reinterpret_cast<const shortx8*>(&Al[(w * 16 + (lane & 15)) * 32 + 8 * (lane >> 4)]);
#pragma unroll
        for (int nt = 0; nt < 16; ++nt) {
            shortx8 bf = *reinterpret_cast<const shortx8*>(&Bl[(nt * 16 + (lane & 15)) * 32 + 8 * (lane >> 4)]);
            acc[nt] = __builtin_amdgcn_mfma_f32_16x16x32_bf16(af, bf, acc[nt], 0, 0, 0);
        }
        __syncthreads();
    }
    const int col = lane & 15;
    const int rbase = m0 + w * 16 + 4 * (lane >> 4);
#pragma unroll
    for (int nt = 0; nt < 16; ++nt) {
        int gn = nt * 16 + col;
        bool isq = gn < 128;
        int oc = isq ? gn : gn - 128;
        float b = isq ? bq[oc] : bk[oc];
        unsigned short* O = isq ? qbf : kbf;
#pragma unroll
        for (int reg = 0; reg < 4; ++reg) {
            int gm = rbase + reg;
            if (gm < M) {
                float v = acc[nt][reg] + b;
                v = v > 0.f ? v : 0.01f * v;
                O[(size_t)gm * 128 + oc] = f2bf(v);
            }
        }
    }
}

// ---------------- logits in sorted order: p[pos] = exp(q[r].k[s]/sqrt(d)) --
__global__ __launch_bounds__(256)
void logits_sorted(const unsigned short* __restrict__ qbf, const unsigned short* __restrict__ kbf,
                   const int* __restrict__ sidx, const int* __restrict__ ridx,
                   const int* __restrict__ perm, float* __restrict__ p) {
    const int tid = threadIdx.x;
    const int pos = blockIdx.x * 64 + (tid >> 2);
    const int qt = tid & 3;
    int e = perm[pos];
    int s = sidx[e], r = ridx[e];
    const uint4* kp = reinterpret_cast<const uint4*>(kbf + (size_t)s * 128 + qt * 32);
    const uint4* qp = reinterpret_cast<const uint4*>(qbf + (size_t)r * 128 + qt * 32);
    float acq = 0.f;
#pragma unroll
    for (int i = 0; i < 4; ++i) {
        uint4 qa = qp[i], ka = kp[i];
        acq += bflo(qa.x) * bflo(ka.x) + bfhi(qa.x) * bfhi(ka.x);
        acq += bflo(qa.y) * bflo(ka.y) + bfhi(qa.y) * bfhi(ka.y);
        acq += bflo(qa.z) * bflo(ka.z) + bfhi(qa.z) * bfhi(ka.z);
        acq += bflo(qa.w) * bflo(ka.w) + bfhi(qa.w) * bfhi(ka.w);
    }
    acq += __shfl_xor(acq, 1);
    acq += __shfl_xor(acq, 2);
    if (qt == 0) p[pos] = __expf(acq * 0.08838834764831845f);
}

// ---------------- streaming V projection (natural order) -> bf16 ----------
// BM=128 consecutive edges/block, 512 threads. Pure sequential HBM traffic.
// LDS 64KB: [0,32768) Wv frags (aliased as Vl post-loop), [32768,65536) A frags.
__global__ __launch_bounds__(512)
void v_gemm_stream(const float* __restrict__ Ed, const unsigned short* __restrict__ wv_bf,
                   const float* __restrict__ bv, unsigned short* __restrict__ vout) {
    __shared__ __align__(16) char smem[65536];
    unsigned short* Vl = reinterpret_cast<unsigned short*>(smem);   // alias, post-loop

    const int tid = threadIdx.x;
    const int lane = tid & 63, w = tid >> 6;
    const size_t m0 = (size_t)blockIdx.x * 128;      // NE % 128 == 0

    const int erow = tid >> 2;
    const int qt = tid & 3;

    // one edge-row quarter (128B) per thread, sequential rows
    const float* arow = Ed + (m0 + erow) * 128;
    float4 fa[4], fb[4];
#pragma unroll
    for (int ks = 0; ks < 4; ++ks) {
        fa[ks] = *reinterpret_cast<const float4*>(arow + qt * 32 + ks * 8);
        fb[ks] = *reinterpret_cast<const float4*>(arow + qt * 32 + ks * 8 + 4);
    }

    // Wv -> fragment-linear
#pragma unroll
    for (int it = 0; it < 4; ++it) {
        int s = tid + it * 512;
        int g = s >> 6, l = s & 63;
        int kt4 = g >> 3, nt = g & 7;
        uint4 v = *reinterpret_cast<const uint4*>(
            wv_bf + (size_t)(nt * 16 + (l & 15)) * 128 + kt4 * 32 + 8 * (l >> 4));
        *reinterpret_cast<uint4*>(smem + s * 16) = v;
    }
    // A -> fragment-linear: frag_id = (erow>>4)*4 + qt
    {
        const int fragbase = 32768 + (((erow >> 4) * 4 + qt) << 10) + ((erow & 15) << 4);
#pragma unroll
        for (int ks = 0; ks < 4; ++ks)
            *reinterpret_cast<shortx8*>(smem + fragbase + ks * 256) = pack8(fa[ks], fb[ks]);
    }
    __syncthreads();

    floatx4 acc[8];
#pragma unroll
    for (int i = 0; i < 8; ++i) acc[i] = (floatx4)0.0f;
#pragma unroll
    for (int kt = 0; kt < 4; ++kt) {
        shortx8 af = *reinterpret_cast<const shortx8*>(
            smem + 32768 + ((w * 4 + kt) << 10) + (lane << 4));
#pragma unroll
        for (int nt = 0; nt < 8; ++nt) {
            shortx8 bfr = *reinterpret_cast<const shortx8*>(smem + (((kt * 8 + nt) * 64 + lane) << 4));
            acc[nt] = __builtin_amdgcn_mfma_f32_16x16x32_bf16(af, bfr, acc[nt], 0, 0, 0);
        }
    }
    __syncthreads();     // Wv reads done; alias as Vl

    // bias + lrelu -> bf16 rows in LDS
    const int colb = lane & 15;
    const int rquad = w * 16 + 4 * (lane >> 4);
#pragma unroll
    for (int nt = 0; nt < 8; ++nt) {
        float b = bv[nt * 16 + colb];
#pragma unroll
        for (int reg = 0; reg < 4; ++reg) {
            float v = acc[nt][reg] + b;
            v = v > 0.f ? v : 0.01f * v;
            Vl[(rquad + reg) * 128 + nt * 16 + colb] = f2bf(v);
        }
    }
    __syncthreads();

    // coalesced LDS -> global copy (32KB)
#pragma unroll
    for (int it = 0; it < 4; ++it) {
        int s = tid + it * 512;
        *reinterpret_cast<uint4*>(vout + m0 * 128 + (size_t)s * 8) =
            *reinterpret_cast<const uint4*>(smem + s * 16);
    }
}

// ---------------- gather + segment reduce + normalize: 1 wave per node ----
__global__ __launch_bounds__(256)
void gather_reduce(const unsigned short* __restrict__ vbf, const float* __restrict__ p,
                   const int* __restrict__ perm, const int* __restrict__ offs2,
                   float* __restrict__ out) {
    const int lane = threadIdx.x & 63, w = threadIdx.x >> 6;
    const int n = blockIdx.x * 4 + w;            // 12500*4 == NN
    const int g = lane >> 4;                     // edge sub-slot 0..3
    const int c = lane & 15;                     // col group (8 cols)
    const int start = offs2[n], end = offs2[n + 1];

    float acc[8];
#pragma unroll
    for (int i = 0; i < 8; ++i) acc[i] = 0.f;
    float ds = 0.f;

    for (int pos = start + g; pos < end; pos += 4) {
        int e = perm[pos];                        // broadcast within 16-lane group
        float ps = p[pos];                        // broadcast
        uint4 vv = *reinterpret_cast<const uint4*>(vbf + (size_t)e * 128 + c * 8);
        acc[0] += ps * bflo(vv.x); acc[1] += ps * bfhi(vv.x);
        acc[2] += ps * bflo(vv.y); acc[3] += ps * bfhi(vv.y);
        acc[4] += ps * bflo(vv.z); acc[5] += ps * bfhi(vv.z);
        acc[6] += ps * bflo(vv.w); acc[7] += ps * bfhi(vv.w);
        ds += ps;
    }
    // reduce across the 4 edge sub-slots (lanes l, l^16, l^32, l^48)
#pragma unroll
    for (int i = 0; i < 8; ++i) {
        acc[i] += __shfl_xor(acc[i], 32);
        acc[i] += __shfl_xor(acc[i], 16);
    }
    ds += __shfl_xor(ds, 32);
    ds += __shfl_xor(ds, 16);

    if (g == 0) {
        float inv = ds > 0.f ? 1.0f / ds : 0.f;
        float4 o0 = make_float4(acc[0] * inv, acc[1] * inv, acc[2] * inv, acc[3] * inv);
        float4 o1 = make_float4(acc[4] * inv, acc[5] * inv, acc[6] * inv, acc[7] * inv);
        float* dst = out + (size_t)n * 128 + c * 8;
        *reinterpret_cast<float4*>(dst) = o0;
        *reinterpret_cast<float4*>(dst + 4) = o1;
    }
}

extern "C" void kernel_launch(void* const* d_in, const int* in_sizes, int n_in,
                              void* d_out, int out_size, void* d_ws, size_t ws_size,
                              hipStream_t stream) {
    const float* nodes = (const float*)d_in[0];
    const float* edges = (const float*)d_in[1];
    const int*   eidx  = (const int*)d_in[2];     // row0 = sender, row1 = receiver
    const float* Wq = (const float*)d_in[3];
    const float* bq = (const float*)d_in[4];
    const float* Wk = (const float*)d_in[5];
    const float* bk = (const float*)d_in[6];
    const float* Wv = (const float*)d_in[7];
    const float* bv = (const float*)d_in[8];
    const int* sidx = eidx;
    const int* ridx = eidx + NE;

    // workspace layout (16B aligned):
    char* ws = (char*)d_ws;
    unsigned short* wq_bf = (unsigned short*)ws;          // Wq||Wk stacked, then Wv
    unsigned short* wv_bf = wq_bf + 65536;
    unsigned short* q_bf  = (unsigned short*)(ws + 163840);
    unsigned short* k_bf  = q_bf + (size_t)NN * 128;
    char* ws2 = ws + 163840 + 2 * (size_t)NN * 128 * 2;   // after q,k (25.6 MB)
    int*   cnt   = (int*)ws2;                             // NN
    int*   offs  = cnt + NN;                              // NN (cursor)
    int*   offs2 = offs + NN;                             // NN+1 (pristine CSR)
    int*   perm  = offs2 + NN + 4;                        // NE
    float* p     = (float*)(perm + NE);                   // NE
    unsigned short* v_bf = (unsigned short*)(p + NE);     // NE*128 bf16 (410 MB)
    float* out = (float*)d_out;

    init_cnt<<<(NN + 255) / 256, 256, 0, stream>>>(cnt);
    cast_w_kernel<<<320, 256, 0, stream>>>(Wq, Wk, Wv, wq_bf);
    hist_kernel<<<(NE + 255) / 256, 256, 0, stream>>>(ridx, cnt);
    scan_kernel<<<1, 1024, 0, stream>>>(cnt, offs, offs2);
    scatter_kernel<<<(NE + 255) / 256, 256, 0, stream>>>(ridx, offs, perm);
    proj_qk<<<(NN + 63) / 64, 256, 0, stream>>>(nodes, wq_bf, bq, bk, q_bf, k_bf, NN);
    logits_sorted<<<NE / 64, 256, 0, stream>>>(q_bf, k_bf, sidx, ridx, perm, p);
    v_gemm_stream<<<NE / 128, 512, 0, stream>>>(edges, wv_bf, bv, v_bf);
    gather_reduce<<<NN / 4, 256, 0, stream>>>(v_bf, p, perm, offs2, out);
}

// Round 7
// 741.994 us; speedup vs baseline: 1.2038x; 1.1847x over previous
//
#include <hip/hip_runtime.h>
#include <hip/hip_bf16.h>
#include <cstdint>

#define NN 50000
#define NE 1600000
#define DV 256
#define DA 128

using floatx4 = __attribute__((ext_vector_type(4))) float;
using shortx8 = __attribute__((ext_vector_type(8))) short;

__device__ __forceinline__ unsigned short f2bf(float f) {
    union { float f; uint32_t u; } v; v.f = f;
    uint32_t u = v.u;
    uint32_t r = (u + 0x7FFFu + ((u >> 16) & 1u)) >> 16;   // RNE
    return (unsigned short)r;
}
__device__ __forceinline__ float bflo(uint32_t u) {
    union { uint32_t u; float f; } v; v.u = u << 16; return v.f;
}
__device__ __forceinline__ float bfhi(uint32_t u) {
    union { uint32_t u; float f; } v; v.u = u & 0xFFFF0000u; return v.f;
}
__device__ __forceinline__ shortx8 pack8(float4 a, float4 b) {
    shortx8 u;
    u[0] = (short)f2bf(a.x); u[1] = (short)f2bf(a.y);
    u[2] = (short)f2bf(a.z); u[3] = (short)f2bf(a.w);
    u[4] = (short)f2bf(b.x); u[5] = (short)f2bf(b.y);
    u[6] = (short)f2bf(b.z); u[7] = (short)f2bf(b.w);
    return u;
}

// ---------------- zero cnt ------------------------------------------------
__global__ void init_cnt(int* __restrict__ cnt) {
    int i = blockIdx.x * blockDim.x + threadIdx.x;
    if (i < NN) cnt[i] = 0;
}

// ---------------- cast weights fp32 -> bf16 -------------------------------
__global__ void cast_w_kernel(const float* __restrict__ wq, const float* __restrict__ wk,
                              const float* __restrict__ wv, unsigned short* __restrict__ out) {
    int i = blockIdx.x * blockDim.x + threadIdx.x;
    if (i < 32768)       out[i] = f2bf(wq[i]);
    else if (i < 65536)  out[i] = f2bf(wk[i - 32768]);
    else if (i < 81920)  out[i] = f2bf(wv[i - 65536]);
}

// ---------------- CSR build -----------------------------------------------
__global__ void hist_kernel(const int* __restrict__ ridx, int* __restrict__ cnt) {
    int e = blockIdx.x * blockDim.x + threadIdx.x;
    if (e < NE) atomicAdd(&cnt[ridx[e]], 1);
}

// single-block exclusive scan; offs = cursor copy, offs2 = pristine CSR
__global__ __launch_bounds__(1024)
void scan_kernel(const int* __restrict__ cnt, int* __restrict__ offs, int* __restrict__ offs2) {
    __shared__ int part[1024];
    const int tid = threadIdx.x;
    const int PER = (NN + 1023) / 1024;   // 49
    int base = tid * PER;
    int s = 0;
    for (int i = 0; i < PER; ++i) { int idx = base + i; if (idx < NN) s += cnt[idx]; }
    part[tid] = s;
    __syncthreads();
    for (int off = 1; off < 1024; off <<= 1) {
        int v = (tid >= off) ? part[tid - off] : 0;
        __syncthreads();
        part[tid] += v;
        __syncthreads();
    }
    int excl = (tid == 0) ? 0 : part[tid - 1];
    for (int i = 0; i < PER; ++i) {
        int idx = base + i;
        if (idx < NN) { offs[idx] = excl; offs2[idx] = excl; excl += cnt[idx]; }
    }
    if (tid == 0) offs2[NN] = NE;
}

// ---------------- fused Q,K projection: [NN,256] x [256,256]^T ------------
__global__ __launch_bounds__(256)
void proj_qk(const float* __restrict__ A, const unsigned short* __restrict__ Wst,
             const float* __restrict__ bq, const float* __restrict__ bk,
             unsigned short* __restrict__ qbf, unsigned short* __restrict__ kbf, int M) {
    __shared__ unsigned short Al[64 * 32];
    __shared__ unsigned short Bl[256 * 32];
    const int tid = threadIdx.x;
    const int lane = tid & 63, w = tid >> 6;
    const int m0 = blockIdx.x * 64;
    constexpr int K = 256;

    floatx4 acc[16];
#pragma unroll
    for (int i = 0; i < 16; ++i) acc[i] = (floatx4)0.0f;

    for (int kk = 0; kk < K; kk += 32) {
#pragma unroll
        for (int it = 0; it < 2; ++it) {
            int j = tid + it * 256;
            int row = j >> 3;
            int c4 = (j & 7) * 4;
            float4 f = make_float4(0.f, 0.f, 0.f, 0.f);
            int gm = m0 + row;
            if (gm < M) f = *reinterpret_cast<const float4*>(A + (size_t)gm * K + kk + c4);
            ushort4 u; u.x = f2bf(f.x); u.y = f2bf(f.y); u.z = f2bf(f.z); u.w = f2bf(f.w);
            *reinterpret_cast<ushort4*>(&Al[row * 32 + c4]) = u;
        }
#pragma unroll
        for (int it = 0; it < 4; ++it) {
            int j = tid + it * 256;
            int row = j >> 2;
            int c8 = (j & 3) * 8;
            uint4 v = *reinterpret_cast<const uint4*>(Wst + (size_t)row * K + kk + c8);
            *reinterpret_cast<uint4*>(&Bl[row * 32 + c8]) = v;
        }
        __syncthreads();
        shortx8 af = *reinterpret_cast<const shortx8*>(&Al[(w * 16 + (lane & 15)) * 32 + 8 * (lane >> 4)]);
#pragma unroll
        for (int nt = 0; nt < 16; ++nt) {
            shortx8 bf = *reinterpret_cast<const shortx8*>(&Bl[(nt * 16 + (lane & 15)) * 32 + 8 * (lane >> 4)]);
            acc[nt] = __builtin_amdgcn_mfma_f32_16x16x32_bf16(af, bf, acc[nt], 0, 0, 0);
        }
        __syncthreads();
    }
    const int col = lane & 15;
    const int rbase = m0 + w * 16 + 4 * (lane >> 4);
#pragma unroll
    for (int nt = 0; nt < 16; ++nt) {
        int gn = nt * 16 + col;
        bool isq = gn < 128;
        int oc = isq ? gn : gn - 128;
        float b = isq ? bq[oc] : bk[oc];
        unsigned short* O = isq ? qbf : kbf;
#pragma unroll
        for (int reg = 0; reg < 4; ++reg) {
            int gm = rbase + reg;
            if (gm < M) {
                float v = acc[nt][reg] + b;
                v = v > 0.f ? v : 0.01f * v;
                O[(size_t)gm * 128 + oc] = f2bf(v);
            }
        }
    }
}

// ---- streaming V-GEMM, writes V rows to receiver-sorted slots ------------
// BM=128 sequential edges/block, 512 threads. Sequential edge reads;
// sorted slot claimed via CSR cursor atomic; scattered 256B WRITES only.
// LDS: [0,32768) Wv frags; [32768,65536) A frags (aliased as V-out rows
// post-MFMA); [65536,66048) pos_l[128].
__global__ __launch_bounds__(512)
void v_gemm_scat(const float* __restrict__ Ed, const unsigned short* __restrict__ wv_bf,
                 const float* __restrict__ bv,
                 const int* __restrict__ ridx, const int* __restrict__ sidx,
                 int* __restrict__ cursor,
                 unsigned short* __restrict__ vsort, int* __restrict__ ssort) {
    __shared__ __align__(16) char smem[66048];
    unsigned short* Vl = reinterpret_cast<unsigned short*>(smem + 32768);  // alias of A frags
    int* pos_l = reinterpret_cast<int*>(smem + 65536);

    const int tid = threadIdx.x;
    const int lane = tid & 63, w = tid >> 6;
    const size_t m0 = (size_t)blockIdx.x * 128;    // NE % 128 == 0
    const int erow = tid >> 2;                     // edge slot 0..127
    const int qt = tid & 3;                        // row quarter
    const size_t e = m0 + erow;

    // sequential edge row quarter (128B burst per thread)
    const float* arow = Ed + e * 128;
    float4 fa[4], fb[4];
#pragma unroll
    for (int ks = 0; ks < 4; ++ks) {
        fa[ks] = *reinterpret_cast<const float4*>(arow + qt * 32 + ks * 8);
        fb[ks] = *reinterpret_cast<const float4*>(arow + qt * 32 + ks * 8 + 4);
    }

    // claim sorted slot (one atomic per edge), record sender at that slot
    if (qt == 0) {
        int r = ridx[e];
        int pos = atomicAdd(&cursor[r], 1);
        pos_l[erow] = pos;
        ssort[pos] = sidx[e];
    }

    // Wv -> fragment-linear (frag (kt,nt): lane l = B[k=kt*32+8*(l>>4)][n=nt*16+(l&15)])
#pragma unroll
    for (int it = 0; it < 4; ++it) {
        int s = tid + it * 512;
        int g = s >> 6, l = s & 63;
        int kt4 = g >> 3, nt = g & 7;
        uint4 v = *reinterpret_cast<const uint4*>(
            wv_bf + (size_t)(nt * 16 + (l & 15)) * 128 + kt4 * 32 + 8 * (l >> 4));
        *reinterpret_cast<uint4*>(smem + s * 16) = v;
    }
    // A -> fragment-linear: frag_id = (erow>>4)*4 + qt
    {
        const int fragbase = 32768 + (((erow >> 4) * 4 + qt) << 10) + ((erow & 15) << 4);
#pragma unroll
        for (int ks = 0; ks < 4; ++ks)
            *reinterpret_cast<shortx8*>(smem + fragbase + ks * 256) = pack8(fa[ks], fb[ks]);
    }
    __syncthreads();

    floatx4 acc[8];
#pragma unroll
    for (int i = 0; i < 8; ++i) acc[i] = (floatx4)0.0f;
#pragma unroll
    for (int kt = 0; kt < 4; ++kt) {
        shortx8 af = *reinterpret_cast<const shortx8*>(
            smem + 32768 + ((w * 4 + kt) << 10) + (lane << 4));
#pragma unroll
        for (int nt = 0; nt < 8; ++nt) {
            shortx8 bfr = *reinterpret_cast<const shortx8*>(smem + (((kt * 8 + nt) * 64 + lane) << 4));
            acc[nt] = __builtin_amdgcn_mfma_f32_16x16x32_bf16(af, bfr, acc[nt], 0, 0, 0);
        }
    }
    __syncthreads();     // all A-frag reads done before overwriting region

    // bias + lrelu -> bf16 rows in LDS (A region)
    const int colb = lane & 15;
    const int rquad = w * 16 + 4 * (lane >> 4);
#pragma unroll
    for (int nt = 0; nt < 8; ++nt) {
        float b = bv[nt * 16 + colb];
#pragma unroll
        for (int reg = 0; reg < 4; ++reg) {
            float v = acc[nt][reg] + b;
            v = v > 0.f ? v : 0.01f * v;
            Vl[(rquad + reg) * 128 + nt * 16 + colb] = f2bf(v);
        }
    }
    __syncthreads();

    // scatter rows to sorted slots: 16 lanes per row -> one 256B burst
#pragma unroll
    for (int it = 0; it < 4; ++it) {
        int rr = it * 32 + (tid >> 4);
        int c = tid & 15;
        uint4 v = *reinterpret_cast<const uint4*>(smem + 32768 + rr * 256 + c * 16);
        *reinterpret_cast<uint4*>(vsort + (size_t)pos_l[rr] * 128 + c * 8) = v;
    }
}

// ---- gather: per-node wave, sequential V segment, logits inline ----------
__global__ __launch_bounds__(256)
void gather_reduce2(const unsigned short* __restrict__ vsort, const int* __restrict__ ssort,
                    const unsigned short* __restrict__ qbf, const unsigned short* __restrict__ kbf,
                    const int* __restrict__ offs2, float* __restrict__ out) {
    const int lane = threadIdx.x & 63, w = threadIdx.x >> 6;
    const int n = blockIdx.x * 4 + w;            // 12500*4 == NN
    const int g = lane >> 4;                     // edge sub-slot 0..3
    const int c = lane & 15;                     // col group (8 cols)
    const int start = offs2[n], end = offs2[n + 1];

    // q fragment: 8 dims per lane (same for all 4 sub-slots)
    uint4 qv = *reinterpret_cast<const uint4*>(qbf + (size_t)n * 128 + c * 8);

    float acc[8];
#pragma unroll
    for (int i = 0; i < 8; ++i) acc[i] = 0.f;
    float ds = 0.f;

    for (int pos = start + g; pos < end; pos += 4) {
        int s = ssort[pos];                       // broadcast within group
        uint4 kv = *reinterpret_cast<const uint4*>(kbf + (size_t)s * 128 + c * 8);
        float d = bflo(qv.x) * bflo(kv.x) + bfhi(qv.x) * bfhi(kv.x)
                + bflo(qv.y) * bflo(kv.y) + bfhi(qv.y) * bfhi(kv.y)
                + bflo(qv.z) * bflo(kv.z) + bfhi(qv.z) * bfhi(kv.z)
                + bflo(qv.w) * bflo(kv.w) + bfhi(qv.w) * bfhi(kv.w);
        d += __shfl_xor(d, 1);
        d += __shfl_xor(d, 2);
        d += __shfl_xor(d, 4);
        d += __shfl_xor(d, 8);
        float p = __expf(d * 0.08838834764831845f);
        uint4 vv = *reinterpret_cast<const uint4*>(vsort + (size_t)pos * 128 + c * 8);
        acc[0] += p * bflo(vv.x); acc[1] += p * bfhi(vv.x);
        acc[2] += p * bflo(vv.y); acc[3] += p * bfhi(vv.y);
        acc[4] += p * bflo(vv.z); acc[5] += p * bfhi(vv.z);
        acc[6] += p * bflo(vv.w); acc[7] += p * bfhi(vv.w);
        ds += p;
    }
    // reduce across the 4 edge sub-slots
#pragma unroll
    for (int i = 0; i < 8; ++i) {
        acc[i] += __shfl_xor(acc[i], 32);
        acc[i] += __shfl_xor(acc[i], 16);
    }
    ds += __shfl_xor(ds, 32);
    ds += __shfl_xor(ds, 16);

    if (g == 0) {
        float inv = ds > 0.f ? 1.0f / ds : 0.f;
        float4 o0 = make_float4(acc[0] * inv, acc[1] * inv, acc[2] * inv, acc[3] * inv);
        float4 o1 = make_float4(acc[4] * inv, acc[5] * inv, acc[6] * inv, acc[7] * inv);
        float* dst = out + (size_t)n * 128 + c * 8;
        *reinterpret_cast<float4*>(dst) = o0;
        *reinterpret_cast<float4*>(dst + 4) = o1;
    }
}

extern "C" void kernel_launch(void* const* d_in, const int* in_sizes, int n_in,
                              void* d_out, int out_size, void* d_ws, size_t ws_size,
                              hipStream_t stream) {
    const float* nodes = (const float*)d_in[0];
    const float* edges = (const float*)d_in[1];
    const int*   eidx  = (const int*)d_in[2];     // row0 = sender, row1 = receiver
    const float* Wq = (const float*)d_in[3];
    const float* bq = (const float*)d_in[4];
    const float* Wk = (const float*)d_in[5];
    const float* bk = (const float*)d_in[6];
    const float* Wv = (const float*)d_in[7];
    const float* bv = (const float*)d_in[8];
    const int* sidx = eidx;
    const int* ridx = eidx + NE;

    // workspace layout (16B aligned):
    char* ws = (char*)d_ws;
    unsigned short* wq_bf = (unsigned short*)ws;          // Wq||Wk stacked, then Wv
    unsigned short* wv_bf = wq_bf + 65536;
    unsigned short* q_bf  = (unsigned short*)(ws + 163840);
    unsigned short* k_bf  = q_bf + (size_t)NN * 128;
    char* ws2 = ws + 163840 + 2 * (size_t)NN * 128 * 2;   // after q,k (25.6 MB)
    int*   cnt   = (int*)ws2;                             // NN
    int*   offs  = cnt + NN;                              // NN (cursor)
    int*   offs2 = offs + NN;                             // NN+1 (pristine CSR)
    int*   ssort = offs2 + NN + 4;                        // NE (sender per sorted slot)
    unsigned short* vsort = (unsigned short*)(ssort + NE);// NE*128 bf16 (410 MB)
    float* out = (float*)d_out;

    init_cnt<<<(NN + 255) / 256, 256, 0, stream>>>(cnt);
    cast_w_kernel<<<320, 256, 0, stream>>>(Wq, Wk, Wv, wq_bf);
    hist_kernel<<<(NE + 255) / 256, 256, 0, stream>>>(ridx, cnt);
    scan_kernel<<<1, 1024, 0, stream>>>(cnt, offs, offs2);
    proj_qk<<<(NN + 63) / 64, 256, 0, stream>>>(nodes, wq_bf, bq, bk, q_bf, k_bf, NN);
    v_gemm_scat<<<NE / 128, 512, 0, stream>>>(edges, wv_bf, bv, ridx, sidx, offs,
                                              vsort, ssort);
    gather_reduce2<<<NN / 4, 256, 0, stream>>>(vsort, ssort, q_bf, k_bf, offs2, out);
}